// Round 1
// baseline (253.077 us; speedup 1.0000x reference)
//
#include <hip/hip_runtime.h>
#include <hip/hip_bf16.h>

typedef __bf16 bf16_t;
typedef __bf16 bf16x8 __attribute__((ext_vector_type(8)));
typedef float f32x4 __attribute__((ext_vector_type(4)));

#define MFMA16(A, B, C) __builtin_amdgcn_mfma_f32_16x16x32_bf16(A, B, C, 0, 0, 0)

// Problem constants
// x: [8][512][4096] fp32; w_in: [192][512]; b_in: [192]; w_out: [512][64]; b_out: [512]
// y: [8][512][4096] fp32

// ---------------------------------------------------------------------------
// Kernel 1: qkv = w_in @ x + b_in   (per batch GEMM [192x512] x [512x4096])
// Q -> q_r [8][4096][64] bf16 (row-major queries)
// K -> k_r [8][4096][64] bf16
// V -> v_t [8][64][4096] bf16 (original channel-major layout)
// Grid: (64 n-tiles, 3 m-tiles, 8 batches), 256 threads.
// ---------------------------------------------------------------------------
__global__ __launch_bounds__(256) void qkv_kernel(
    const float* __restrict__ x,
    const float* __restrict__ w_in,
    const float* __restrict__ b_in,
    bf16_t* __restrict__ q_r,
    bf16_t* __restrict__ k_r,
    bf16_t* __restrict__ v_t)
{
    const int b    = blockIdx.z;
    const int mt   = blockIdx.y;          // 0:Q 1:K 2:V (64 channels each)
    const int n0   = blockIdx.x * 64;
    const int t    = threadIdx.x;
    const int lane = t & 63;
    const int wave = t >> 6;
    const int wm   = wave >> 1;           // 0..1
    const int wn   = wave & 1;            // 0..1

    __shared__ bf16_t Xs[64][56];         // [n][c] transposed x tile, stride 56 (112B, 16B-aligned)

    const float* xb = x + (size_t)b * 512 * 4096;

    f32x4 acc[2][2] = {};                 // [mf][nf]

    for (int k0 = 0; k0 < 512; k0 += 32) {
        __syncthreads();
        // stage x[k0..k0+32][n0..n0+64] -> Xs[n][c] (bf16, transposed)
        {
            const int c  = t >> 3;            // 0..31
            const int nb = (t & 7) * 8;       // 0..56
            const float* src = xb + (size_t)(k0 + c) * 4096 + n0 + nb;
            float4 v0 = *(const float4*)(src);
            float4 v1 = *(const float4*)(src + 4);
            Xs[nb + 0][c] = (bf16_t)v0.x; Xs[nb + 1][c] = (bf16_t)v0.y;
            Xs[nb + 2][c] = (bf16_t)v0.z; Xs[nb + 3][c] = (bf16_t)v0.w;
            Xs[nb + 4][c] = (bf16_t)v1.x; Xs[nb + 5][c] = (bf16_t)v1.y;
            Xs[nb + 6][c] = (bf16_t)v1.z; Xs[nb + 7][c] = (bf16_t)v1.w;
        }
        __syncthreads();

        // A fragments from w_in (fp32 -> bf16), row = m, k contiguous
        bf16x8 afrag[2];
        #pragma unroll
        for (int mf = 0; mf < 2; ++mf) {
            const int m = mt * 64 + wm * 32 + mf * 16 + (lane & 15);
            const float* wsrc = w_in + (size_t)m * 512 + k0 + (lane >> 4) * 8;
            float4 a0 = *(const float4*)(wsrc);
            float4 a1 = *(const float4*)(wsrc + 4);
            bf16x8 af;
            af[0] = (bf16_t)a0.x; af[1] = (bf16_t)a0.y; af[2] = (bf16_t)a0.z; af[3] = (bf16_t)a0.w;
            af[4] = (bf16_t)a1.x; af[5] = (bf16_t)a1.y; af[6] = (bf16_t)a1.z; af[7] = (bf16_t)a1.w;
            afrag[mf] = af;
        }
        #pragma unroll
        for (int nf = 0; nf < 2; ++nf) {
            const int n = wn * 32 + nf * 16 + (lane & 15);
            bf16x8 bfrag = *(const bf16x8*)&Xs[n][(lane >> 4) * 8];
            #pragma unroll
            for (int mf = 0; mf < 2; ++mf)
                acc[mf][nf] = MFMA16(afrag[mf], bfrag, acc[mf][nf]);
        }
    }

    // epilogue: + bias, store in the layout attention wants
    #pragma unroll
    for (int mf = 0; mf < 2; ++mf) {
        #pragma unroll
        for (int nf = 0; nf < 2; ++nf) {
            const int cloc = wm * 32 + mf * 16 + (lane >> 4) * 4;  // local channel base (0..60)
            const int m    = mt * 64 + cloc;                       // global out-channel base
            const int n    = n0 + wn * 32 + nf * 16 + (lane & 15);
            #pragma unroll
            for (int r = 0; r < 4; ++r) {
                const float val = acc[mf][nf][r] + b_in[m + r];
                if (mt == 0) {
                    q_r[((size_t)b * 4096 + n) * 64 + cloc + r] = (bf16_t)val;
                } else if (mt == 1) {
                    k_r[((size_t)b * 4096 + n) * 64 + cloc + r] = (bf16_t)val;
                } else {
                    v_t[((size_t)b * 64 + cloc + r) * 4096 + n] = (bf16_t)val;
                }
            }
        }
    }
}

// ---------------------------------------------------------------------------
// Kernel 2: flash attention. Per block: one batch, 64 queries (4 waves x 16).
// scores = (Q K^T)/8, softmax over keys (online), out = P V.
// o_r [8][4096][64] bf16.
// Grid: (64 q-tiles, 8 batches), 256 threads.
// ---------------------------------------------------------------------------
__global__ __launch_bounds__(256) void attn_kernel(
    const bf16_t* __restrict__ q_r,
    const bf16_t* __restrict__ k_r,
    const bf16_t* __restrict__ v_t,
    bf16_t* __restrict__ o_r)
{
    const int b    = blockIdx.y;
    const int nq0  = blockIdx.x * 64;
    const int t    = threadIdx.x;
    const int lane = t & 63;
    const int wave = t >> 6;

    __shared__ bf16_t Ks[64][72];        // [kv_row][c]
    __shared__ bf16_t Vs[64][72];        // [c][kv_row]  (from v_t channel-major)
    __shared__ bf16_t Ps[4][16][72];     // per-wave P tile [q][kv]

    // Q fragments held in registers for the whole KV loop
    bf16x8 qfrag[2];
    {
        const bf16_t* qsrc =
            q_r + ((size_t)b * 4096 + nq0 + wave * 16 + (lane & 15)) * 64 + (lane >> 4) * 8;
        qfrag[0] = *(const bf16x8*)(qsrc);
        qfrag[1] = *(const bf16x8*)(qsrc + 32);
    }

    float m_run[4], l_run[4];
    f32x4 oacc[4];                        // [cf] output accumulators (16 q x 64 c per wave)
    #pragma unroll
    for (int r = 0; r < 4; ++r) { m_run[r] = -1e30f; l_run[r] = 0.f; }
    #pragma unroll
    for (int cf = 0; cf < 4; ++cf) oacc[cf] = (f32x4){0.f, 0.f, 0.f, 0.f};

    const bf16_t* kb = k_r + (size_t)b * 4096 * 64;
    const bf16_t* vb = v_t + (size_t)b * 64 * 4096;

    for (int m0 = 0; m0 < 4096; m0 += 64) {
        __syncthreads();
        // stage K tile and V tile
        {
            const int row = t >> 2;          // 0..63
            const int cb  = (t & 3) * 16;    // 0,16,32,48
            const bf16_t* ksrc = kb + (size_t)(m0 + row) * 64 + cb;
            *(bf16x8*)&Ks[row][cb]     = *(const bf16x8*)(ksrc);
            *(bf16x8*)&Ks[row][cb + 8] = *(const bf16x8*)(ksrc + 8);
            const bf16_t* vsrc = vb + (size_t)row * 4096 + m0 + cb;
            *(bf16x8*)&Vs[row][cb]     = *(const bf16x8*)(vsrc);
            *(bf16x8*)&Vs[row][cb + 8] = *(const bf16x8*)(vsrc + 8);
        }
        __syncthreads();

        // S = Q K^T  (unscaled; scale 1/8 applied in softmax)
        f32x4 s[4];
        #pragma unroll
        for (int nf = 0; nf < 4; ++nf) {
            bf16x8 kf0 = *(const bf16x8*)&Ks[nf * 16 + (lane & 15)][(lane >> 4) * 8];
            bf16x8 kf1 = *(const bf16x8*)&Ks[nf * 16 + (lane & 15)][32 + (lane >> 4) * 8];
            f32x4 a = (f32x4){0.f, 0.f, 0.f, 0.f};
            a = MFMA16(qfrag[0], kf0, a);
            a = MFMA16(qfrag[1], kf1, a);
            s[nf] = a;
        }

        // online softmax; lane holds rows (lane>>4)*4+r, cols (lane&15)+16*nf
        float sc[4], rs[4];
        #pragma unroll
        for (int r = 0; r < 4; ++r) {
            float mx = fmaxf(fmaxf(s[0][r], s[1][r]), fmaxf(s[2][r], s[3][r]));
            #pragma unroll
            for (int off = 1; off < 16; off <<= 1)
                mx = fmaxf(mx, __shfl_xor(mx, off));
            const float tmax = mx * 0.125f;
            const float nm = fmaxf(m_run[r], tmax);
            sc[r] = __expf(m_run[r] - nm);
            m_run[r] = nm;
            rs[r] = 0.f;
        }
        #pragma unroll
        for (int nf = 0; nf < 4; ++nf) {
            #pragma unroll
            for (int r = 0; r < 4; ++r) {
                const float p = __expf(s[nf][r] * 0.125f - m_run[r]);
                rs[r] += p;
                Ps[wave][(lane >> 4) * 4 + r][nf * 16 + (lane & 15)] = (bf16_t)p;
            }
        }
        #pragma unroll
        for (int r = 0; r < 4; ++r) {
            float sum = rs[r];
            #pragma unroll
            for (int off = 1; off < 16; off <<= 1)
                sum += __shfl_xor(sum, off);
            l_run[r] = l_run[r] * sc[r] + sum;
        }
        #pragma unroll
        for (int cf = 0; cf < 4; ++cf) {
            #pragma unroll
            for (int r = 0; r < 4; ++r) oacc[cf][r] *= sc[r];
        }
        __syncthreads();   // P visible to own wave via LDS; also fences Vs reads vs next staging

        // O += P V
        #pragma unroll
        for (int ms = 0; ms < 2; ++ms) {
            bf16x8 pf = *(const bf16x8*)&Ps[wave][lane & 15][ms * 32 + (lane >> 4) * 8];
            #pragma unroll
            for (int cf = 0; cf < 4; ++cf) {
                bf16x8 vf = *(const bf16x8*)&Vs[cf * 16 + (lane & 15)][ms * 32 + (lane >> 4) * 8];
                oacc[cf] = MFMA16(pf, vf, oacc[cf]);
            }
        }
    }

    // epilogue: normalize and store (B, N, 64) bf16
    #pragma unroll
    for (int cf = 0; cf < 4; ++cf) {
        #pragma unroll
        for (int r = 0; r < 4; ++r) {
            const int n = nq0 + wave * 16 + (lane >> 4) * 4 + r;
            const int c = cf * 16 + (lane & 15);
            o_r[((size_t)b * 4096 + n) * 64 + c] = (bf16_t)(oacc[cf][r] / l_run[r]);
        }
    }
}

// ---------------------------------------------------------------------------
// Kernel 3: y = w_out @ attn_out + b_out + x   ([512x64] x [64x4096] per batch)
// Pure-register MFMA; K=64 in 2 k-steps. Grid: (64 n-tiles, 8 m-tiles, 8 b).
// ---------------------------------------------------------------------------
__global__ __launch_bounds__(256) void out_kernel(
    const float* __restrict__ x,
    const float* __restrict__ w_out,
    const float* __restrict__ b_out,
    const bf16_t* __restrict__ o_r,
    float* __restrict__ y)
{
    const int b    = blockIdx.z;
    const int mt0  = blockIdx.y * 64;
    const int n0   = blockIdx.x * 64;
    const int t    = threadIdx.x;
    const int lane = t & 63;
    const int wave = t >> 6;
    const int wm   = wave >> 1;
    const int wn   = wave & 1;

    f32x4 acc[2][2] = {};

    bf16x8 afrag[2][2];   // [mf][ks] from w_out fp32
    #pragma unroll
    for (int mf = 0; mf < 2; ++mf) {
        const int m = mt0 + wm * 32 + mf * 16 + (lane & 15);
        #pragma unroll
        for (int ks = 0; ks < 2; ++ks) {
            const float* src = w_out + (size_t)m * 64 + ks * 32 + (lane >> 4) * 8;
            float4 a0 = *(const float4*)(src);
            float4 a1 = *(const float4*)(src + 4);
            bf16x8 af;
            af[0] = (bf16_t)a0.x; af[1] = (bf16_t)a0.y; af[2] = (bf16_t)a0.z; af[3] = (bf16_t)a0.w;
            af[4] = (bf16_t)a1.x; af[5] = (bf16_t)a1.y; af[6] = (bf16_t)a1.z; af[7] = (bf16_t)a1.w;
            afrag[mf][ks] = af;
        }
    }

    #pragma unroll
    for (int nf = 0; nf < 2; ++nf) {
        const int n = n0 + wn * 32 + nf * 16 + (lane & 15);
        const bf16_t* osrc = o_r + ((size_t)b * 4096 + n) * 64 + (lane >> 4) * 8;
        bf16x8 b0 = *(const bf16x8*)(osrc);
        bf16x8 b1 = *(const bf16x8*)(osrc + 32);
        #pragma unroll
        for (int mf = 0; mf < 2; ++mf) {
            acc[mf][nf] = MFMA16(afrag[mf][0], b0, acc[mf][nf]);
            acc[mf][nf] = MFMA16(afrag[mf][1], b1, acc[mf][nf]);
        }
    }

    #pragma unroll
    for (int mf = 0; mf < 2; ++mf) {
        #pragma unroll
        for (int nf = 0; nf < 2; ++nf) {
            const int n     = n0 + wn * 32 + nf * 16 + (lane & 15);
            const int mbase = mt0 + wm * 32 + mf * 16 + (lane >> 4) * 4;
            #pragma unroll
            for (int r = 0; r < 4; ++r) {
                const int m = mbase + r;
                const size_t idx = ((size_t)b * 512 + m) * 4096 + n;
                y[idx] = acc[mf][nf][r] + b_out[m] + x[idx];
            }
        }
    }
}

// ---------------------------------------------------------------------------
extern "C" void kernel_launch(void* const* d_in, const int* in_sizes, int n_in,
                              void* d_out, int out_size, void* d_ws, size_t ws_size,
                              hipStream_t stream)
{
    const float* x     = (const float*)d_in[0];
    const float* w_in  = (const float*)d_in[1];
    const float* b_in  = (const float*)d_in[2];
    const float* w_out = (const float*)d_in[3];
    const float* b_out = (const float*)d_in[4];
    float* y = (float*)d_out;

    char* ws = (char*)d_ws;
    bf16_t* q_r = (bf16_t*)(ws);                    // 8*4096*64*2 = 4 MiB
    bf16_t* k_r = (bf16_t*)(ws + 4194304);          // 4 MiB
    bf16_t* v_t = (bf16_t*)(ws + 8388608);          // 4 MiB
    bf16_t* o_r = (bf16_t*)(ws + 12582912);         // 4 MiB

    qkv_kernel<<<dim3(64, 3, 8), 256, 0, stream>>>(x, w_in, b_in, q_r, k_r, v_t);
    attn_kernel<<<dim3(64, 8), 256, 0, stream>>>(q_r, k_r, v_t, o_r);
    out_kernel<<<dim3(64, 8, 8), 256, 0, stream>>>(x, w_out, b_out, o_r, y);
}

// Round 2
// 238.000 us; speedup vs baseline: 1.0633x; 1.0633x over previous
//
#include <hip/hip_runtime.h>
#include <hip/hip_bf16.h>

typedef __bf16 bf16_t;
typedef __bf16 bf16x8 __attribute__((ext_vector_type(8)));
typedef float f32x4 __attribute__((ext_vector_type(4)));
typedef float f32x16 __attribute__((ext_vector_type(16)));
typedef unsigned int u32x4 __attribute__((ext_vector_type(4)));

#define MFMA16(A,B,C) __builtin_amdgcn_mfma_f32_16x16x32_bf16(A,B,C,0,0,0)
#define MFMA32(A,B,C) __builtin_amdgcn_mfma_f32_32x32x16_bf16(A,B,C,0,0,0)

// exp(s/8) computed as exp2(s * 0.125*log2(e)); the scale is folded into Q.
#define QSCALE 0.18033688011112042f

__device__ inline unsigned pk_bf16(float lo, float hi) {
  unsigned r;
  asm("v_cvt_pk_bf16_f32 %0, %1, %2" : "=v"(r) : "v"(lo), "v"(hi));
  return r;
}
__device__ inline bf16x8 frag4(unsigned a, unsigned b, unsigned c, unsigned d) {
  union { u32x4 u; bf16x8 f; } x;
  x.u = (u32x4){a, b, c, d};
  return x.f;
}
__device__ inline void gload16(const bf16_t* g, const bf16_t* l) {
  __builtin_amdgcn_global_load_lds(
      (const __attribute__((address_space(1))) unsigned int*)g,
      (__attribute__((address_space(3))) unsigned int*)l, 16, 0, 0);
}

// ---------------------------------------------------------------------------
// Kernel 1: qkv = w_in @ x + b_in   (per batch GEMM [192x512] x [512x4096])
// Q -> q_r [8][4096][64] bf16, PRE-SCALED by 0.125*log2(e)
// K -> k_r [8][4096][64] bf16
// V -> v_t [8][64][4096] bf16 (channel-major)
// ---------------------------------------------------------------------------
__global__ __launch_bounds__(256) void qkv_kernel(
    const float* __restrict__ x,
    const float* __restrict__ w_in,
    const float* __restrict__ b_in,
    bf16_t* __restrict__ q_r,
    bf16_t* __restrict__ k_r,
    bf16_t* __restrict__ v_t)
{
    const int b    = blockIdx.z;
    const int mt   = blockIdx.y;          // 0:Q 1:K 2:V
    const int n0   = blockIdx.x * 64;
    const int t    = threadIdx.x;
    const int lane = t & 63;
    const int wave = t >> 6;
    const int wm   = wave >> 1;
    const int wn   = wave & 1;

    __shared__ bf16_t Xs[64][56];

    const float* xb = x + (size_t)b * 512 * 4096;

    f32x4 acc[2][2] = {};

    for (int k0 = 0; k0 < 512; k0 += 32) {
        __syncthreads();
        {
            const int c  = t >> 3;
            const int nb = (t & 7) * 8;
            const float* src = xb + (size_t)(k0 + c) * 4096 + n0 + nb;
            float4 v0 = *(const float4*)(src);
            float4 v1 = *(const float4*)(src + 4);
            Xs[nb + 0][c] = (bf16_t)v0.x; Xs[nb + 1][c] = (bf16_t)v0.y;
            Xs[nb + 2][c] = (bf16_t)v0.z; Xs[nb + 3][c] = (bf16_t)v0.w;
            Xs[nb + 4][c] = (bf16_t)v1.x; Xs[nb + 5][c] = (bf16_t)v1.y;
            Xs[nb + 6][c] = (bf16_t)v1.z; Xs[nb + 7][c] = (bf16_t)v1.w;
        }
        __syncthreads();

        bf16x8 afrag[2];
        #pragma unroll
        for (int mf = 0; mf < 2; ++mf) {
            const int m = mt * 64 + wm * 32 + mf * 16 + (lane & 15);
            const float* wsrc = w_in + (size_t)m * 512 + k0 + (lane >> 4) * 8;
            float4 a0 = *(const float4*)(wsrc);
            float4 a1 = *(const float4*)(wsrc + 4);
            bf16x8 af;
            af[0] = (bf16_t)a0.x; af[1] = (bf16_t)a0.y; af[2] = (bf16_t)a0.z; af[3] = (bf16_t)a0.w;
            af[4] = (bf16_t)a1.x; af[5] = (bf16_t)a1.y; af[6] = (bf16_t)a1.z; af[7] = (bf16_t)a1.w;
            afrag[mf] = af;
        }
        #pragma unroll
        for (int nf = 0; nf < 2; ++nf) {
            const int n = wn * 32 + nf * 16 + (lane & 15);
            bf16x8 bfrag = *(const bf16x8*)&Xs[n][(lane >> 4) * 8];
            #pragma unroll
            for (int mf = 0; mf < 2; ++mf)
                acc[mf][nf] = MFMA16(afrag[mf], bfrag, acc[mf][nf]);
        }
    }

    #pragma unroll
    for (int mf = 0; mf < 2; ++mf) {
        #pragma unroll
        for (int nf = 0; nf < 2; ++nf) {
            const int cloc = wm * 32 + mf * 16 + (lane >> 4) * 4;
            const int m    = mt * 64 + cloc;
            const int n    = n0 + wn * 32 + nf * 16 + (lane & 15);
            #pragma unroll
            for (int r = 0; r < 4; ++r) {
                float val = acc[mf][nf][r] + b_in[m + r];
                if (mt == 0) {
                    val *= QSCALE;
                    q_r[((size_t)b * 4096 + n) * 64 + cloc + r] = (bf16_t)val;
                } else if (mt == 1) {
                    k_r[((size_t)b * 4096 + n) * 64 + cloc + r] = (bf16_t)val;
                } else {
                    v_t[((size_t)b * 64 + cloc + r) * 4096 + n] = (bf16_t)val;
                }
            }
        }
    }
}

// ---------------------------------------------------------------------------
// Kernel 2: fused flash attention + out-proj + bias + skip.
// 4 waves/block, 32 q-rows per wave (swapped-operand 32x32x16 MFMA).
// Grid: (32 q-tiles, 8 batches) = 256 blocks, 256 threads.
//
// Layouts (m74/m101-verified 32x32 mappings):
//   A-frag: row = lane&31, k = (lane>>5)*8 + j
//   B-frag: col = lane&31, k = (lane>>5)*8 + j
//   C/D:    col = lane&31, row = (reg&3) + 8*(reg>>2) + 4*(lane>>5)
// QK^T: S^T = mfma(K, Q)  -> lane owns one q-row (col), kv spread over regs.
// PV:   O^T = mfma(V^T, P^T) -> q stays the lane axis, c over regs.
// K/V LDS: [row][64] linear, 16B-chunk XOR swizzle (chunk ^= row&7), filled by
// global_load_lds with pre-swizzled global source (linear LDS dest).
// ---------------------------------------------------------------------------
__global__ __launch_bounds__(256) void attn_kernel(
    const bf16_t* __restrict__ q_r, const bf16_t* __restrict__ k_r,
    const bf16_t* __restrict__ v_t, const float* __restrict__ x,
    const float* __restrict__ w_out, const float* __restrict__ b_out,
    float* __restrict__ y)
{
    const int b    = blockIdx.y;
    const int t    = threadIdx.x;
    const int lane = t & 63;
    const int wave = t >> 6;
    const int lq   = lane & 31;
    const int hi   = lane >> 5;
    const int nq   = blockIdx.x * 128 + wave * 32 + lq;   // this lane's q index

    __shared__ bf16_t Ks[2][64 * 64];
    __shared__ bf16_t Vs[2][64 * 64];

    // staging constants (8 rows x 8 chunks of 16B per 1KB wave-instr)
    const int r8  = lane >> 3;        // row within 8-row group
    const int csw = (lane & 7) ^ r8;  // pre-swizzled source chunk
    const bf16_t* kb = k_r + (size_t)b * 4096 * 64;
    const bf16_t* vb = v_t + (size_t)b * 64 * 4096;

    auto STAGE = [&](int buf, int m0) {
        #pragma unroll
        for (int i = 0; i < 2; ++i) {
            const int rr = wave * 16 + i * 8;             // 8-row group base
            gload16(kb + (size_t)(m0 + rr + r8) * 64 + csw * 8, &Ks[buf][rr * 64]);
            gload16(vb + (size_t)(rr + r8) * 4096 + m0 + csw * 8, &Vs[buf][rr * 64]);
        }
    };

    // Q fragments (entire d=64 in 4 k-steps), pre-scaled in qkv
    bf16x8 qf[4];
    {
        const bf16_t* qp = q_r + ((size_t)b * 4096 + nq) * 64 + hi * 8;
        #pragma unroll
        for (int ks = 0; ks < 4; ++ks) qf[ks] = *(const bf16x8*)(qp + ks * 16);
    }

    f32x16 oa0 = {}, oa1 = {};        // O^T accum: c = ct*32 + crow, col q
    float m_run = -3.0e38f, l_run = 0.f;

    STAGE(0, 0);
    asm volatile("s_waitcnt vmcnt(0)" ::: "memory");
    __builtin_amdgcn_s_barrier();

    for (int tt = 0; tt < 64; ++tt) {
        const int cur = tt & 1;
        if (tt < 63) STAGE(cur ^ 1, (tt + 1) * 64);

        // --- QK^T: S^T[kv][q], two 32-kv subtiles ---
        f32x16 sA = {}, sB = {};
        #pragma unroll
        for (int ks = 0; ks < 4; ++ks) {
            const int ch = ((ks * 2 + hi) ^ (lq & 7)) * 8;
            bf16x8 k0 = *(const bf16x8*)&Ks[cur][lq * 64 + ch];
            bf16x8 k1 = *(const bf16x8*)&Ks[cur][(32 + lq) * 64 + ch];
            sA = MFMA32(k0, qf[ks], sA);
            sB = MFMA32(k1, qf[ks], sB);
        }

        // --- online softmax, log2 domain, defer-max THR=8 ---
        float tm;
        {
            float a[16];
            #pragma unroll
            for (int r = 0; r < 16; ++r) a[r] = fmaxf(sA[r], sB[r]);
            #pragma unroll
            for (int r = 0; r < 8; ++r) a[r] = fmaxf(a[r], a[r + 8]);
            #pragma unroll
            for (int r = 0; r < 4; ++r) a[r] = fmaxf(a[r], a[r + 4]);
            tm = fmaxf(fmaxf(a[0], a[1]), fmaxf(a[2], a[3]));
            tm = fmaxf(tm, __shfl_xor(tm, 32));
        }
        if (__any(tm > m_run + 8.f)) {
            const float nm = fmaxf(m_run, tm);
            const float sc = __builtin_amdgcn_exp2f(m_run - nm);
            m_run = nm;
            l_run *= sc;
            #pragma unroll
            for (int r = 0; r < 16; ++r) { oa0[r] *= sc; oa1[r] *= sc; }
        }
        #pragma unroll
        for (int r = 0; r < 16; ++r) sA[r] = __builtin_amdgcn_exp2f(sA[r] - m_run);
        #pragma unroll
        for (int r = 0; r < 16; ++r) sB[r] = __builtin_amdgcn_exp2f(sB[r] - m_run);
        {
            float a[16];
            #pragma unroll
            for (int r = 0; r < 16; ++r) a[r] = sA[r] + sB[r];
            #pragma unroll
            for (int r = 0; r < 8; ++r) a[r] += a[r + 8];
            #pragma unroll
            for (int r = 0; r < 4; ++r) a[r] += a[r + 4];
            float ps = (a[0] + a[1]) + (a[2] + a[3]);
            ps += __shfl_xor(ps, 32);
            l_run += ps;
        }

        // --- pack P -> bf16 B-frags (half-wave exchange) + PV ---
        #pragma unroll
        for (int s = 0; s < 2; ++s) {
            const f32x16 pe = s ? sB : sA;
            const unsigned w0 = pk_bf16(pe[0], pe[1]),  w1 = pk_bf16(pe[2], pe[3]);
            const unsigned w2 = pk_bf16(pe[4], pe[5]),  w3 = pk_bf16(pe[6], pe[7]);
            const unsigned w4 = pk_bf16(pe[8], pe[9]),  w5 = pk_bf16(pe[10], pe[11]);
            const unsigned w6 = pk_bf16(pe[12], pe[13]), w7 = pk_bf16(pe[14], pe[15]);
            const unsigned e0 = __shfl_xor((int)(hi ? w0 : w2), 32);
            const unsigned e1 = __shfl_xor((int)(hi ? w1 : w3), 32);
            const unsigned e2 = __shfl_xor((int)(hi ? w4 : w6), 32);
            const unsigned e3 = __shfl_xor((int)(hi ? w5 : w7), 32);
            bf16x8 pf0 = frag4(hi ? e0 : w0, hi ? e1 : w1, hi ? w2 : e0, hi ? w3 : e1);
            bf16x8 pf1 = frag4(hi ? e2 : w4, hi ? e3 : w5, hi ? w6 : e2, hi ? w7 : e3);

            const int K0 = (s * 2 + 0) * 2 + hi;   // kv chunk for k-slot 0
            const int K1 = (s * 2 + 1) * 2 + hi;
            bf16x8 v00 = *(const bf16x8*)&Vs[cur][lq * 64 + ((K0 ^ (lq & 7)) * 8)];
            bf16x8 v10 = *(const bf16x8*)&Vs[cur][(32 + lq) * 64 + ((K0 ^ (lq & 7)) * 8)];
            bf16x8 v01 = *(const bf16x8*)&Vs[cur][lq * 64 + ((K1 ^ (lq & 7)) * 8)];
            bf16x8 v11 = *(const bf16x8*)&Vs[cur][(32 + lq) * 64 + ((K1 ^ (lq & 7)) * 8)];
            oa0 = MFMA32(v00, pf0, oa0);
            oa1 = MFMA32(v10, pf0, oa1);
            oa0 = MFMA32(v01, pf1, oa0);
            oa1 = MFMA32(v11, pf1, oa1);
        }

        asm volatile("s_waitcnt vmcnt(0) lgkmcnt(0)" ::: "memory");
        __builtin_amdgcn_s_barrier();
    }

    // --- epilogue: normalize O, pack to B-frags, fused out-proj + skip ---
    const float inv = 1.f / l_run;
    bf16x8 obf[4];
    #pragma unroll
    for (int ct = 0; ct < 2; ++ct) {
        f32x16 o = ct ? oa1 : oa0;
        #pragma unroll
        for (int r = 0; r < 16; ++r) o[r] *= inv;
        const unsigned w0 = pk_bf16(o[0], o[1]),   w1 = pk_bf16(o[2], o[3]);
        const unsigned w2 = pk_bf16(o[4], o[5]),   w3 = pk_bf16(o[6], o[7]);
        const unsigned w4 = pk_bf16(o[8], o[9]),   w5 = pk_bf16(o[10], o[11]);
        const unsigned w6 = pk_bf16(o[12], o[13]), w7 = pk_bf16(o[14], o[15]);
        const unsigned e0 = __shfl_xor((int)(hi ? w0 : w2), 32);
        const unsigned e1 = __shfl_xor((int)(hi ? w1 : w3), 32);
        const unsigned e2 = __shfl_xor((int)(hi ? w4 : w6), 32);
        const unsigned e3 = __shfl_xor((int)(hi ? w5 : w7), 32);
        obf[ct * 2 + 0] = frag4(hi ? e0 : w0, hi ? e1 : w1, hi ? w2 : e0, hi ? w3 : e1);
        obf[ct * 2 + 1] = frag4(hi ? e2 : w4, hi ? e3 : w5, hi ? w6 : e2, hi ? w7 : e3);
    }

    #pragma unroll 2
    for (int mt = 0; mt < 16; ++mt) {
        f32x16 acc = {};
        #pragma unroll
        for (int ks = 0; ks < 4; ++ks) {
            const float* wp = w_out + (size_t)(mt * 32 + lq) * 64 + ks * 16 + hi * 8;
            float4 a0 = *(const float4*)wp;
            float4 a1 = *(const float4*)(wp + 4);
            bf16x8 af = frag4(pk_bf16(a0.x, a0.y), pk_bf16(a0.z, a0.w),
                              pk_bf16(a1.x, a1.y), pk_bf16(a1.z, a1.w));
            acc = MFMA32(af, obf[ks], acc);
        }
        #pragma unroll
        for (int r = 0; r < 16; ++r) {
            const int m = mt * 32 + (r & 3) + 8 * (r >> 2) + 4 * hi;
            const size_t idx = ((size_t)b * 512 + m) * 4096 + nq;
            y[idx] = acc[r] + b_out[m] + x[idx];
        }
    }
}

// ---------------------------------------------------------------------------
extern "C" void kernel_launch(void* const* d_in, const int* in_sizes, int n_in,
                              void* d_out, int out_size, void* d_ws, size_t ws_size,
                              hipStream_t stream)
{
    const float* x     = (const float*)d_in[0];
    const float* w_in  = (const float*)d_in[1];
    const float* b_in  = (const float*)d_in[2];
    const float* w_out = (const float*)d_in[3];
    const float* b_out = (const float*)d_in[4];
    float* y = (float*)d_out;

    char* ws = (char*)d_ws;
    bf16_t* q_r = (bf16_t*)(ws);                    // 4 MiB
    bf16_t* k_r = (bf16_t*)(ws + 4194304);          // 4 MiB
    bf16_t* v_t = (bf16_t*)(ws + 8388608);          // 4 MiB

    qkv_kernel<<<dim3(64, 3, 8), 256, 0, stream>>>(x, w_in, b_in, q_r, k_r, v_t);
    attn_kernel<<<dim3(32, 8), 256, 0, stream>>>(q_r, k_r, v_t, x, w_out, b_out, y);
}

// Round 3
// 165.736 us; speedup vs baseline: 1.5270x; 1.4360x over previous
//
#include <hip/hip_runtime.h>
#include <hip/hip_bf16.h>

typedef __bf16 bf16_t;
typedef __bf16 bf16x8 __attribute__((ext_vector_type(8)));
typedef float f32x4 __attribute__((ext_vector_type(4)));
typedef float f32x16 __attribute__((ext_vector_type(16)));
typedef unsigned int u32x4 __attribute__((ext_vector_type(4)));

#define MFMA16(A,B,C) __builtin_amdgcn_mfma_f32_16x16x32_bf16(A,B,C,0,0,0)
#define MFMA32(A,B,C) __builtin_amdgcn_mfma_f32_32x32x16_bf16(A,B,C,0,0,0)

// exp(s/8) computed as exp2(s * 0.125*log2(e)); the scale is folded into Q.
#define QSCALE 0.18033688011112042f

__device__ inline unsigned pk_bf16(float lo, float hi) {
  unsigned r;
  asm("v_cvt_pk_bf16_f32 %0, %1, %2" : "=v"(r) : "v"(lo), "v"(hi));
  return r;
}
__device__ inline bf16x8 frag4(unsigned a, unsigned b, unsigned c, unsigned d) {
  union { u32x4 u; bf16x8 f; } x;
  x.u = (u32x4){a, b, c, d};
  return x.f;
}
__device__ inline void gload16(const bf16_t* g, const bf16_t* l) {
  __builtin_amdgcn_global_load_lds(
      (const __attribute__((address_space(1))) unsigned int*)g,
      (__attribute__((address_space(3))) unsigned int*)l, 16, 0, 0);
}

// ---------------------------------------------------------------------------
// Kernel 1: qkv = w_in @ x + b_in   (per batch GEMM [192x512] x [512x4096])
// Q -> q_r [8][4096][64] bf16, PRE-SCALED by 0.125*log2(e)
// K -> k_r [8][4096][64] bf16
// V -> v_t [8][64][4096] bf16 (channel-major)
// ---------------------------------------------------------------------------
__global__ __launch_bounds__(256) void qkv_kernel(
    const float* __restrict__ x,
    const float* __restrict__ w_in,
    const float* __restrict__ b_in,
    bf16_t* __restrict__ q_r,
    bf16_t* __restrict__ k_r,
    bf16_t* __restrict__ v_t)
{
    const int b    = blockIdx.z;
    const int mt   = blockIdx.y;          // 0:Q 1:K 2:V
    const int n0   = blockIdx.x * 64;
    const int t    = threadIdx.x;
    const int lane = t & 63;
    const int wave = t >> 6;
    const int wm   = wave >> 1;
    const int wn   = wave & 1;

    __shared__ bf16_t Xs[64][56];

    const float* xb = x + (size_t)b * 512 * 4096;

    f32x4 acc[2][2] = {};

    for (int k0 = 0; k0 < 512; k0 += 32) {
        __syncthreads();
        {
            const int c  = t >> 3;
            const int nb = (t & 7) * 8;
            const float* src = xb + (size_t)(k0 + c) * 4096 + n0 + nb;
            float4 v0 = *(const float4*)(src);
            float4 v1 = *(const float4*)(src + 4);
            Xs[nb + 0][c] = (bf16_t)v0.x; Xs[nb + 1][c] = (bf16_t)v0.y;
            Xs[nb + 2][c] = (bf16_t)v0.z; Xs[nb + 3][c] = (bf16_t)v0.w;
            Xs[nb + 4][c] = (bf16_t)v1.x; Xs[nb + 5][c] = (bf16_t)v1.y;
            Xs[nb + 6][c] = (bf16_t)v1.z; Xs[nb + 7][c] = (bf16_t)v1.w;
        }
        __syncthreads();

        bf16x8 afrag[2];
        #pragma unroll
        for (int mf = 0; mf < 2; ++mf) {
            const int m = mt * 64 + wm * 32 + mf * 16 + (lane & 15);
            const float* wsrc = w_in + (size_t)m * 512 + k0 + (lane >> 4) * 8;
            float4 a0 = *(const float4*)(wsrc);
            float4 a1 = *(const float4*)(wsrc + 4);
            bf16x8 af;
            af[0] = (bf16_t)a0.x; af[1] = (bf16_t)a0.y; af[2] = (bf16_t)a0.z; af[3] = (bf16_t)a0.w;
            af[4] = (bf16_t)a1.x; af[5] = (bf16_t)a1.y; af[6] = (bf16_t)a1.z; af[7] = (bf16_t)a1.w;
            afrag[mf] = af;
        }
        #pragma unroll
        for (int nf = 0; nf < 2; ++nf) {
            const int n = wn * 32 + nf * 16 + (lane & 15);
            bf16x8 bfrag = *(const bf16x8*)&Xs[n][(lane >> 4) * 8];
            #pragma unroll
            for (int mf = 0; mf < 2; ++mf)
                acc[mf][nf] = MFMA16(afrag[mf], bfrag, acc[mf][nf]);
        }
    }

    #pragma unroll
    for (int mf = 0; mf < 2; ++mf) {
        #pragma unroll
        for (int nf = 0; nf < 2; ++nf) {
            const int cloc = wm * 32 + mf * 16 + (lane >> 4) * 4;
            const int m    = mt * 64 + cloc;
            const int n    = n0 + wn * 32 + nf * 16 + (lane & 15);
            #pragma unroll
            for (int r = 0; r < 4; ++r) {
                float val = acc[mf][nf][r] + b_in[m + r];
                if (mt == 0) {
                    val *= QSCALE;
                    q_r[((size_t)b * 4096 + n) * 64 + cloc + r] = (bf16_t)val;
                } else if (mt == 1) {
                    k_r[((size_t)b * 4096 + n) * 64 + cloc + r] = (bf16_t)val;
                } else {
                    v_t[((size_t)b * 64 + cloc + r) * 4096 + n] = (bf16_t)val;
                }
            }
        }
    }
}

// ---------------------------------------------------------------------------
// Kernel 2: flash attention PARTIAL (KV-split by 4).
// Grid: (32 q-tiles, 8 batches, 4 splits) = 1024 blocks, 256 threads.
// Each block: 128 q-rows (4 waves x 32 q), KV range split*1024..+1024.
// Writes per q-row: normalized partial O (bf16, B-frag element order) + (m,l).
// ---------------------------------------------------------------------------
__global__ __launch_bounds__(256) void attn_partial_kernel(
    const bf16_t* __restrict__ q_r, const bf16_t* __restrict__ k_r,
    const bf16_t* __restrict__ v_t,
    bf16_t* __restrict__ Opart, float* __restrict__ ml)
{
    const int b     = blockIdx.y;
    const int split = blockIdx.z;
    const int kv0   = split * 1024;
    const int t     = threadIdx.x;
    const int lane  = t & 63;
    const int wave  = t >> 6;
    const int lq    = lane & 31;
    const int hi    = lane >> 5;
    const int nq    = blockIdx.x * 128 + wave * 32 + lq;

    __shared__ bf16_t Ks[2][64 * 64];
    __shared__ bf16_t Vs[2][64 * 64];

    const int r8  = lane >> 3;
    const int csw = (lane & 7) ^ r8;
    const bf16_t* kb = k_r + (size_t)b * 4096 * 64;
    const bf16_t* vb = v_t + (size_t)b * 64 * 4096;

    auto STAGE = [&](int buf, int m0) {
        #pragma unroll
        for (int i = 0; i < 2; ++i) {
            const int rr = wave * 16 + i * 8;
            gload16(kb + (size_t)(m0 + rr + r8) * 64 + csw * 8, &Ks[buf][rr * 64]);
            gload16(vb + (size_t)(rr + r8) * 4096 + m0 + csw * 8, &Vs[buf][rr * 64]);
        }
    };

    bf16x8 qf[4];
    {
        const bf16_t* qp = q_r + ((size_t)b * 4096 + nq) * 64 + hi * 8;
        #pragma unroll
        for (int ks = 0; ks < 4; ++ks) qf[ks] = *(const bf16x8*)(qp + ks * 16);
    }

    f32x16 oa0 = {}, oa1 = {};
    float m_run = -3.0e38f, l_run = 0.f;

    STAGE(0, kv0);
    asm volatile("s_waitcnt vmcnt(0)" ::: "memory");
    __builtin_amdgcn_s_barrier();

    for (int tt = 0; tt < 16; ++tt) {
        const int cur = tt & 1;
        if (tt < 15) STAGE(cur ^ 1, kv0 + (tt + 1) * 64);

        // --- QK^T: S^T[kv][q], two 32-kv subtiles ---
        f32x16 sA = {}, sB = {};
        #pragma unroll
        for (int ks = 0; ks < 4; ++ks) {
            const int ch = ((ks * 2 + hi) ^ (lq & 7)) * 8;
            bf16x8 k0 = *(const bf16x8*)&Ks[cur][lq * 64 + ch];
            bf16x8 k1 = *(const bf16x8*)&Ks[cur][(32 + lq) * 64 + ch];
            sA = MFMA32(k0, qf[ks], sA);
            sB = MFMA32(k1, qf[ks], sB);
        }

        // --- online softmax, log2 domain, defer-max THR=8 ---
        float tm;
        {
            float a[16];
            #pragma unroll
            for (int r = 0; r < 16; ++r) a[r] = fmaxf(sA[r], sB[r]);
            #pragma unroll
            for (int r = 0; r < 8; ++r) a[r] = fmaxf(a[r], a[r + 8]);
            #pragma unroll
            for (int r = 0; r < 4; ++r) a[r] = fmaxf(a[r], a[r + 4]);
            tm = fmaxf(fmaxf(a[0], a[1]), fmaxf(a[2], a[3]));
            tm = fmaxf(tm, __shfl_xor(tm, 32));
        }
        if (__any(tm > m_run + 8.f)) {
            const float nm = fmaxf(m_run, tm);
            const float sc = __builtin_amdgcn_exp2f(m_run - nm);
            m_run = nm;
            l_run *= sc;
            #pragma unroll
            for (int r = 0; r < 16; ++r) { oa0[r] *= sc; oa1[r] *= sc; }
        }
        #pragma unroll
        for (int r = 0; r < 16; ++r) sA[r] = __builtin_amdgcn_exp2f(sA[r] - m_run);
        #pragma unroll
        for (int r = 0; r < 16; ++r) sB[r] = __builtin_amdgcn_exp2f(sB[r] - m_run);
        {
            float a[16];
            #pragma unroll
            for (int r = 0; r < 16; ++r) a[r] = sA[r] + sB[r];
            #pragma unroll
            for (int r = 0; r < 8; ++r) a[r] += a[r + 8];
            #pragma unroll
            for (int r = 0; r < 4; ++r) a[r] += a[r + 4];
            float ps = (a[0] + a[1]) + (a[2] + a[3]);
            ps += __shfl_xor(ps, 32);
            l_run += ps;
        }

        // --- pack P -> bf16 B-frags (half-wave exchange) + PV ---
        #pragma unroll
        for (int s = 0; s < 2; ++s) {
            const f32x16 pe = s ? sB : sA;
            const unsigned w0 = pk_bf16(pe[0], pe[1]),  w1 = pk_bf16(pe[2], pe[3]);
            const unsigned w2 = pk_bf16(pe[4], pe[5]),  w3 = pk_bf16(pe[6], pe[7]);
            const unsigned w4 = pk_bf16(pe[8], pe[9]),  w5 = pk_bf16(pe[10], pe[11]);
            const unsigned w6 = pk_bf16(pe[12], pe[13]), w7 = pk_bf16(pe[14], pe[15]);
            const unsigned e0 = __shfl_xor((int)(hi ? w0 : w2), 32);
            const unsigned e1 = __shfl_xor((int)(hi ? w1 : w3), 32);
            const unsigned e2 = __shfl_xor((int)(hi ? w4 : w6), 32);
            const unsigned e3 = __shfl_xor((int)(hi ? w5 : w7), 32);
            bf16x8 pf0 = frag4(hi ? e0 : w0, hi ? e1 : w1, hi ? w2 : e0, hi ? w3 : e1);
            bf16x8 pf1 = frag4(hi ? e2 : w4, hi ? e3 : w5, hi ? w6 : e2, hi ? w7 : e3);

            const int K0 = (s * 2 + 0) * 2 + hi;
            const int K1 = (s * 2 + 1) * 2 + hi;
            bf16x8 v00 = *(const bf16x8*)&Vs[cur][lq * 64 + ((K0 ^ (lq & 7)) * 8)];
            bf16x8 v10 = *(const bf16x8*)&Vs[cur][(32 + lq) * 64 + ((K0 ^ (lq & 7)) * 8)];
            bf16x8 v01 = *(const bf16x8*)&Vs[cur][lq * 64 + ((K1 ^ (lq & 7)) * 8)];
            bf16x8 v11 = *(const bf16x8*)&Vs[cur][(32 + lq) * 64 + ((K1 ^ (lq & 7)) * 8)];
            oa0 = MFMA32(v00, pf0, oa0);
            oa1 = MFMA32(v10, pf0, oa1);
            oa0 = MFMA32(v01, pf1, oa0);
            oa1 = MFMA32(v11, pf1, oa1);
        }

        asm volatile("s_waitcnt vmcnt(0) lgkmcnt(0)" ::: "memory");
        __builtin_amdgcn_s_barrier();
    }

    // --- epilogue: normalize, pack to B-frag order, store partials ---
    const float inv = 1.f / l_run;
    bf16x8 obf[4];
    #pragma unroll
    for (int ct = 0; ct < 2; ++ct) {
        f32x16 o = ct ? oa1 : oa0;
        #pragma unroll
        for (int r = 0; r < 16; ++r) o[r] *= inv;
        const unsigned w0 = pk_bf16(o[0], o[1]),   w1 = pk_bf16(o[2], o[3]);
        const unsigned w2 = pk_bf16(o[4], o[5]),   w3 = pk_bf16(o[6], o[7]);
        const unsigned w4 = pk_bf16(o[8], o[9]),   w5 = pk_bf16(o[10], o[11]);
        const unsigned w6 = pk_bf16(o[12], o[13]), w7 = pk_bf16(o[14], o[15]);
        const unsigned e0 = __shfl_xor((int)(hi ? w0 : w2), 32);
        const unsigned e1 = __shfl_xor((int)(hi ? w1 : w3), 32);
        const unsigned e2 = __shfl_xor((int)(hi ? w4 : w6), 32);
        const unsigned e3 = __shfl_xor((int)(hi ? w5 : w7), 32);
        obf[ct * 2 + 0] = frag4(hi ? e0 : w0, hi ? e1 : w1, hi ? w2 : e0, hi ? w3 : e1);
        obf[ct * 2 + 1] = frag4(hi ? e2 : w4, hi ? e3 : w5, hi ? w6 : e2, hi ? w7 : e3);
    }

    bf16_t* op = Opart + (((size_t)(b * 4 + split)) * 4096 + nq) * 64;
    #pragma unroll
    for (int ks = 0; ks < 4; ++ks)
        *(bf16x8*)(op + ks * 16 + hi * 8) = obf[ks];
    if (hi == 0) {
        float2 v; v.x = m_run; v.y = l_run;
        *(float2*)&ml[(((size_t)(b * 4 + split)) * 4096 + nq) * 2] = v;
    }
}

// ---------------------------------------------------------------------------
// Kernel 3: combine partials + out-proj + bias + skip.
// Grid: (64 q-tiles of 64, 8 batches) = 512 blocks, 512 threads (8 waves).
// Waves 0-3 -> q-group 0 (32 q), waves 4-7 -> q-group 1; each wave 4 mt.
// ---------------------------------------------------------------------------
__global__ __launch_bounds__(512) void combine_kernel(
    const bf16_t* __restrict__ Opart, const float* __restrict__ ml,
    const float* __restrict__ x, const float* __restrict__ w_out,
    const float* __restrict__ b_out, float* __restrict__ y)
{
    const int b    = blockIdx.y;
    const int t    = threadIdx.x;
    const int lane = t & 63;
    const int wave = t >> 6;          // 0..7
    const int lq   = lane & 31;
    const int hi   = lane >> 5;
    const int group = wave >> 2;      // 0..1
    const int nq   = blockIdx.x * 64 + group * 32 + lq;

    // merge 4 splits -> normalized O fragments
    float coef[4];
    {
        float m_s[4], l_s[4];
        #pragma unroll
        for (int s = 0; s < 4; ++s) {
            float2 v = *(const float2*)&ml[(((size_t)(b * 4 + s)) * 4096 + nq) * 2];
            m_s[s] = v.x; l_s[s] = v.y;
        }
        const float M = fmaxf(fmaxf(m_s[0], m_s[1]), fmaxf(m_s[2], m_s[3]));
        float L = 0.f;
        #pragma unroll
        for (int s = 0; s < 4; ++s) {
            coef[s] = __builtin_amdgcn_exp2f(m_s[s] - M) * l_s[s];
            L += coef[s];
        }
        const float invL = 1.f / L;
        #pragma unroll
        for (int s = 0; s < 4; ++s) coef[s] *= invL;
    }

    bf16x8 obf[4];
    #pragma unroll
    for (int ks = 0; ks < 4; ++ks) {
        float a8[8] = {};
        #pragma unroll
        for (int s = 0; s < 4; ++s) {
            bf16x8 o = *(const bf16x8*)&Opart[
                (((size_t)(b * 4 + s)) * 4096 + nq) * 64 + ks * 16 + hi * 8];
            #pragma unroll
            for (int j = 0; j < 8; ++j) a8[j] += coef[s] * (float)o[j];
        }
        obf[ks] = frag4(pk_bf16(a8[0], a8[1]), pk_bf16(a8[2], a8[3]),
                        pk_bf16(a8[4], a8[5]), pk_bf16(a8[6], a8[7]));
    }

    // out-proj: this wave handles mt = (wave&3)*4 .. +4 (128 out-channels)
    #pragma unroll 1
    for (int i = 0; i < 4; ++i) {
        const int mt = (wave & 3) * 4 + i;
        f32x16 acc = {};
        #pragma unroll
        for (int ks = 0; ks < 4; ++ks) {
            const float* wp = w_out + (size_t)(mt * 32 + lq) * 64 + ks * 16 + hi * 8;
            float4 a0 = *(const float4*)wp;
            float4 a1 = *(const float4*)(wp + 4);
            bf16x8 af = frag4(pk_bf16(a0.x, a0.y), pk_bf16(a0.z, a0.w),
                              pk_bf16(a1.x, a1.y), pk_bf16(a1.z, a1.w));
            acc = MFMA32(af, obf[ks], acc);
        }
        #pragma unroll
        for (int r = 0; r < 16; ++r) {
            const int m = mt * 32 + (r & 3) + 8 * (r >> 2) + 4 * hi;
            const size_t idx = ((size_t)b * 512 + m) * 4096 + nq;
            y[idx] = acc[r] + b_out[m] + x[idx];
        }
    }
}

// ---------------------------------------------------------------------------
extern "C" void kernel_launch(void* const* d_in, const int* in_sizes, int n_in,
                              void* d_out, int out_size, void* d_ws, size_t ws_size,
                              hipStream_t stream)
{
    const float* x     = (const float*)d_in[0];
    const float* w_in  = (const float*)d_in[1];
    const float* b_in  = (const float*)d_in[2];
    const float* w_out = (const float*)d_in[3];
    const float* b_out = (const float*)d_in[4];
    float* y = (float*)d_out;

    char* ws = (char*)d_ws;
    bf16_t* q_r   = (bf16_t*)(ws);                   // 4 MiB
    bf16_t* k_r   = (bf16_t*)(ws + 4194304);         // 4 MiB
    bf16_t* v_t   = (bf16_t*)(ws + 8388608);         // 4 MiB
    bf16_t* Opart = (bf16_t*)(ws + 12582912);        // 8*4*4096*64*2 = 16 MiB
    float*  ml    = (float*)(ws + 29360128);         // 8*4*4096*2*4  = 1 MiB

    qkv_kernel<<<dim3(64, 3, 8), 256, 0, stream>>>(x, w_in, b_in, q_r, k_r, v_t);
    attn_partial_kernel<<<dim3(32, 8, 4), 256, 0, stream>>>(q_r, k_r, v_t, Opart, ml);
    combine_kernel<<<dim3(64, 8), 512, 0, stream>>>(Opart, ml, x, w_out, b_out, y);
}